// Round 5
// baseline (195.397 us; speedup 1.0000x reference)
//
#include <hip/hip_runtime.h>
#include <math.h>

namespace {
constexpr int kB = 4;
constexpr int kS = 4096;
constexpr int kD = 1024;
constexpr int kM = 128;
constexpr int kC = 64;           // chunk length
constexpr int kNC = kS / kC;     // 64 chunks per batch
constexpr int kRS = kB * kS;     // 16384 rows
constexpr int kNCg = kB * kNC;   // 256 global chunks
constexpr float kLR = 0.01f;
constexpr float kLog2d = -0.0144995696f;   // log2(0.99)
}

typedef __bf16 bf16x8 __attribute__((ext_vector_type(8)));
typedef float  f32x4  __attribute__((ext_vector_type(4)));
typedef unsigned short u16;
typedef unsigned int   u32;

__device__ __forceinline__ u16 f2bf(float f) {
  u32 x = __float_as_uint(f);
  u32 r = (x + 0x7fffu + ((x >> 16) & 1u)) >> 16;   // RNE
  return (u16)r;
}

__device__ __forceinline__ float bf2f(u16 h) {
  return __uint_as_float(((u32)h) << 16);
}

__device__ __forceinline__ void gl_lds16(const void* g, void* l) {
  __builtin_amdgcn_global_load_lds(
      (const __attribute__((address_space(1))) void*)g,
      (__attribute__((address_space(3))) void*)l, 16, 0, 0);
}

__device__ __forceinline__ f32x4 mf(bf16x8 a, bf16x8 b, f32x4 c) {
  return __builtin_amdgcn_mfma_f32_16x16x32_bf16(a, b, c, 0, 0, 0);
}

// ---------------------------------------------------------------------------
// cast Wk|Wv|Wq (concat -> Wkvq[384][1024]) and Wo -> Woh[1024][128], bf16
// ---------------------------------------------------------------------------
__global__ __launch_bounds__(256)
void cast_w_kernel(const float* __restrict__ Wk, const float* __restrict__ Wv,
                   const float* __restrict__ Wq, const float* __restrict__ Wo,
                   u16* __restrict__ Wkvq, u16* __restrict__ Woh)
{
  int i = (blockIdx.x * 256 + threadIdx.x) * 4;   // < 524288
  const float* src;
  u16* dst;
  if (i < 393216) {
    src = (i < 131072) ? Wk + i : (i < 262144) ? Wv + (i - 131072) : Wq + (i - 262144);
    dst = Wkvq + i;
  } else {
    src = Wo + (i - 393216);
    dst = Woh + (i - 393216);
  }
  float4 v = *(const float4*)src;
  ushort4 o;
  o.x = f2bf(v.x); o.y = f2bf(v.y); o.z = f2bf(v.z); o.w = f2bf(v.w);
  *(ushort4*)dst = o;
}

// ---------------------------------------------------------------------------
// Projection: grid (128 row-tiles, 4 slabs). 128x128 tile, BK=32.
//  slab 0: Qg[t][f]  = x.Wq^T + bq      (A=x, B=Wq)
//  slab 1: Kg[t][f]  = x.Wk^T + bk      (A=x, B=Wk)
//  slab 2: VtG[cg][i][u]  = V[u][i]          (A=Wv, B=x -> D[f][t])
//  slab 3: KwtG[cg][j][u] = LR*d^{63-u}*K[u][j]
// x cast fp32->bf16 inline during staging. 16 KB LDS, 2 blocks/CU.
// ---------------------------------------------------------------------------
__global__ __launch_bounds__(256, 2)
void proj_kernel(const float* __restrict__ x, const u16* __restrict__ Wkvq,
                 const float* __restrict__ bk, const float* __restrict__ bv,
                 const float* __restrict__ bq,
                 u16* __restrict__ Qg, u16* __restrict__ Kg,
                 u16* __restrict__ VtG, u16* __restrict__ KwtG)
{
  __shared__ __align__(16) u16 Xs[128 * 32];
  __shared__ __align__(16) u16 Ws[128 * 32];
  const int rt = blockIdx.x, slab = blockIdx.y;
  const int R0 = rt * 128;
  const int tid = threadIdx.x, w = tid >> 6, lane = tid & 63;
  const int fr = lane & 15, qd = lane >> 4;
  const int wro = (slab == 0) ? 256 : (slab == 2) ? 128 : 0;   // Wq/Wk/Wv rows in Wkvq

  // x staging: thread -> row tid>>1, cols (tid&1)*16 .. +15 (fp32 -> bf16)
  const int xr = tid >> 1, xc = (tid & 1) * 16;
  const float* xp = x + (size_t)(R0 + xr) * kD + xc;
  u16* xdst = &Xs[xr * 32 + xc];
  // weight staging: wave w, slot s: row = wro + w*32 + s*16 + (lane>>2)
  const u16* wbase = Wkvq + (size_t)(wro + w * 32 + (lane >> 2)) * kD + (lane & 3) * 8;
  u16* wdst = &Ws[w * 1024];

  float4 xv[4];
#pragma unroll
  for (int q = 0; q < 4; ++q) xv[q] = *(const float4*)(xp + q * 4);

  const int mW = (w >> 1) * 64, nW = (w & 1) * 64;
  f32x4 acc[4][4] = {};
  for (int k0 = 0; k0 < kD; k0 += 32) {
    __syncthreads();
    u16 xh[16];
#pragma unroll
    for (int q = 0; q < 4; ++q) {
      xh[q * 4 + 0] = f2bf(xv[q].x); xh[q * 4 + 1] = f2bf(xv[q].y);
      xh[q * 4 + 2] = f2bf(xv[q].z); xh[q * 4 + 3] = f2bf(xv[q].w);
    }
    *(uint4*)xdst       = *(uint4*)&xh[0];
    *(uint4*)(xdst + 8) = *(uint4*)&xh[8];
    gl_lds16(wbase + k0, wdst);
    gl_lds16(wbase + k0 + (size_t)16 * kD, wdst + 512);
    __syncthreads();
    if (k0 + 32 < kD) {
#pragma unroll
      for (int q = 0; q < 4; ++q) xv[q] = *(const float4*)(xp + k0 + 32 + q * 4);
    }
    const u16* Ap = (slab < 2) ? Xs : Ws;
    const u16* Bp = (slab < 2) ? Ws : Xs;
    bf16x8 av[4], bv8[4];
#pragma unroll
    for (int mi = 0; mi < 4; ++mi) av[mi]  = *(const bf16x8*)&Ap[(mW + mi * 16 + fr) * 32 + qd * 8];
#pragma unroll
    for (int ni = 0; ni < 4; ++ni) bv8[ni] = *(const bf16x8*)&Bp[(nW + ni * 16 + fr) * 32 + qd * 8];
#pragma unroll
    for (int mi = 0; mi < 4; ++mi)
#pragma unroll
      for (int ni = 0; ni < 4; ++ni)
        acc[mi][ni] = mf(av[mi], bv8[ni], acc[mi][ni]);
  }

  if (slab < 2) {
    const float* bp = (slab == 0) ? bq : bk;
    u16* dst = (slab == 0) ? Qg : Kg;
#pragma unroll
    for (int mi = 0; mi < 4; ++mi)
#pragma unroll
      for (int ni = 0; ni < 4; ++ni) {
        const int f = nW + ni * 16 + fr;
        const float bb = bp[f];
#pragma unroll
        for (int r = 0; r < 4; ++r) {
          const int t = mW + mi * 16 + qd * 4 + r;
          dst[(size_t)(R0 + t) * kM + f] = f2bf(acc[mi][ni][r] + bb);
        }
      }
  } else {
    const float* bp = (slab == 2) ? bv : bk;
    u16* dst = (slab == 2) ? VtG : KwtG;
    float scal[4];
#pragma unroll
    for (int ni = 0; ni < 4; ++ni) {
      const int u = (nW + ni * 16 + fr) & 63;
      scal[ni] = (slab == 3) ? kLR * exp2f((float)(63 - u) * kLog2d) : 1.0f;
    }
#pragma unroll
    for (int mi = 0; mi < 4; ++mi)
#pragma unroll
      for (int r = 0; r < 4; ++r) {
        const int i = mW + mi * 16 + qd * 4 + r;   // feature row
        const float bb = bp[i];
#pragma unroll
        for (int ni = 0; ni < 4; ++ni) {
          const int tg = R0 + nW + ni * 16 + fr;   // global time row
          const int cg = tg >> 6, u = tg & 63;
          dst[(size_t)cg * 8192 + i * 64 + u] = f2bf((acc[mi][ni][r] + bb) * scal[ni]);
        }
      }
  }
}

// ---------------------------------------------------------------------------
// intra: grid (64 chunks, 4 batch, 2 z). z splits the feature axis of O1/U.
//   P = Q K^T (dup per z) -> At (LDS roundtrip, reuse Ks region)
//   O1[t][64z+il] = At . Vt_half ; U[64z+il][j] = Vt_half . Kwt
// LDS (u16 el): Qs[0,8192) Ks[8192,16384) (At reuses [8192,12288))
//               VtH[16384,20480) Kwt[20480,28672)   = 56 KB, 2 blocks/CU
// ---------------------------------------------------------------------------
__global__ __launch_bounds__(256, 2)
void intra_kernel(const u16* __restrict__ Qg, const u16* __restrict__ Kg,
                  const u16* __restrict__ VtG, const u16* __restrict__ KwtG,
                  u16* __restrict__ O1g, float* __restrict__ SU)
{
  __shared__ __align__(16) u16 L[28672];
  const int c = blockIdx.x, b = blockIdx.y, z = blockIdx.z;
  const int cg = b * kNC + c;
  const int R0 = cg * kC;
  const int tid = threadIdx.x, w = tid >> 6, lane = tid & 63;
  const int fr = lane & 15, qd = lane >> 4;

  {
    const int rr = lane >> 2, c8 = (lane & 3) * 8;
    const u16* gq = Qg + (size_t)(R0 + rr) * kM + w * 32 + c8;
    const u16* gk = Kg + (size_t)(R0 + rr) * kM + w * 32 + c8;
    u16* lq = &L[w * 2048];
    u16* lk = &L[8192 + w * 2048];
#pragma unroll
    for (int s = 0; s < 4; ++s) {
      gl_lds16(gq + (size_t)s * 16 * kM, lq + s * 512);
      gl_lds16(gk + (size_t)s * 16 * kM, lk + s * 512);
    }
    if (w < 2) {
      const u16* gv = VtG + (size_t)cg * 8192 + (size_t)(64 * z + rr) * 64 + w * 32 + c8;
      u16* lv = &L[16384 + w * 2048];
#pragma unroll
      for (int s = 0; s < 4; ++s)
        gl_lds16(gv + (size_t)(s * 16) * 64, lv + s * 512);
    } else {
      const u16* gw = KwtG + (size_t)cg * 8192 + (size_t)rr * 64 + (w - 2) * 32 + c8;
      u16* lw = &L[20480 + (w - 2) * 4096];
#pragma unroll
      for (int s = 0; s < 8; ++s)
        gl_lds16(gw + (size_t)(s * 16) * 64, lw + s * 512);
    }
  }
  __syncthreads();

  // P = Q K^T  (64x64, wave = 32x32 quadrant)
  const int mB = (w >> 1) * 32, nB = (w & 1) * 32;
  f32x4 p[2][2] = {};
#pragma unroll
  for (int kp = 0; kp < 4; ++kp) {
    bf16x8 a2[2], b2[2];
#pragma unroll
    for (int mi = 0; mi < 2; ++mi) a2[mi] = *(const bf16x8*)&L[kp * 2048 + (mB + mi * 16 + fr) * 32 + qd * 8];
#pragma unroll
    for (int ni = 0; ni < 2; ++ni) b2[ni] = *(const bf16x8*)&L[8192 + kp * 2048 + (nB + ni * 16 + fr) * 32 + qd * 8];
#pragma unroll
    for (int mi = 0; mi < 2; ++mi)
#pragma unroll
      for (int ni = 0; ni < 2; ++ni)
        p[mi][ni] = mf(a2[mi], b2[ni], p[mi][ni]);
  }
  __syncthreads();

  // mask/decay -> At panels [t][32u] at L[8192..12288)
#pragma unroll
  for (int mi = 0; mi < 2; ++mi)
#pragma unroll
    for (int r = 0; r < 4; ++r) {
      const int t = mB + mi * 16 + qd * 4 + r;
#pragma unroll
      for (int ni = 0; ni < 2; ++ni) {
        const int u = nB + ni * 16 + fr;
        float v = 0.f;
        if (u < t) v = kLR * exp2f((float)(t - 1 - u) * kLog2d) * p[mi][ni][r];
        L[8192 + (u >> 5) * 2048 + t * 32 + (u & 31)] = f2bf(v);
      }
    }
  __syncthreads();

  // O1 = At.VtH (t x il), U = VtH.Kwt (il x j)
  const int nB2 = (w & 1) * 32;
  const int mB3 = (w >> 1) * 32;
  const int nB3 = (w & 1) * 64;
  f32x4 o1[2][2] = {}, uu[2][4] = {};
#pragma unroll
  for (int kp = 0; kp < 2; ++kp) {
    bf16x8 at2[2], vb2[2], va2[2], kb4[4];
#pragma unroll
    for (int mi = 0; mi < 2; ++mi) at2[mi] = *(const bf16x8*)&L[8192 + kp * 2048 + (mB + mi * 16 + fr) * 32 + qd * 8];
#pragma unroll
    for (int ni = 0; ni < 2; ++ni) vb2[ni] = *(const bf16x8*)&L[16384 + kp * 2048 + (nB2 + ni * 16 + fr) * 32 + qd * 8];
#pragma unroll
    for (int mi = 0; mi < 2; ++mi) va2[mi] = *(const bf16x8*)&L[16384 + kp * 2048 + (mB3 + mi * 16 + fr) * 32 + qd * 8];
#pragma unroll
    for (int nj = 0; nj < 4; ++nj) kb4[nj] = *(const bf16x8*)&L[20480 + kp * 4096 + (nB3 + nj * 16 + fr) * 32 + qd * 8];
#pragma unroll
    for (int mi = 0; mi < 2; ++mi)
#pragma unroll
      for (int ni = 0; ni < 2; ++ni)
        o1[mi][ni] = mf(at2[mi], vb2[ni], o1[mi][ni]);
#pragma unroll
    for (int mi = 0; mi < 2; ++mi)
#pragma unroll
      for (int nj = 0; nj < 4; ++nj)
        uu[mi][nj] = mf(va2[mi], kb4[nj], uu[mi][nj]);
  }

#pragma unroll
  for (int mi = 0; mi < 2; ++mi)
#pragma unroll
    for (int ni = 0; ni < 2; ++ni)
#pragma unroll
      for (int r = 0; r < 4; ++r) {
        const int t = mB + mi * 16 + qd * 4 + r;
        const int il = nB2 + ni * 16 + fr;
        O1g[(size_t)(R0 + t) * kM + 64 * z + il] = f2bf(o1[mi][ni][r]);
      }
  float* SUc = SU + (size_t)cg * 16384;
#pragma unroll
  for (int mi = 0; mi < 2; ++mi)
#pragma unroll
    for (int nj = 0; nj < 4; ++nj)
#pragma unroll
      for (int r = 0; r < 4; ++r) {
        const int ig = 64 * z + mB3 + mi * 16 + qd * 4 + r;
        const int j = nB3 + nj * 16 + fr;
        SUc[ig * kM + j] = uu[mi][nj][r];
      }
}

// ---------------------------------------------------------------------------
// inter-chunk scan: Sb16[c] = bf16(state before chunk c); carry -> state_out
// ---------------------------------------------------------------------------
__global__ __launch_bounds__(256)
void scan_kernel(const float* __restrict__ SU, u16* __restrict__ Sb16,
                 float* __restrict__ state_out)
{
  const int e = blockIdx.x * 256 + threadIdx.x;   // < kB * 16384
  const int b = e >> 14, ij = e & 16383;
  const float* base = SU + (size_t)b * kNC * 16384 + ij;
  u16* sb = Sb16 + (size_t)b * kNC * 16384 + ij;
  const float dC = exp2f((float)kC * kLog2d);
  float prev = 0.f;
#pragma unroll 8
  for (int c2 = 0; c2 < kNC; ++c2) {
    const float u = base[(size_t)c2 * 16384];
    sb[(size_t)c2 * 16384] = f2bf(prev);
    prev = fmaf(dC, prev, u);
  }
  state_out[e] = prev;
}

// ---------------------------------------------------------------------------
// combine: grid (64, 4, 2). z splits output d-range [512z, 512z+512).
//   O2 = Q S^T ; Out = bf16(O1 + d^t O2) -> LDS A-panels (reuse Q region)
//   y = Out . Woh^T + bo (Woh B-frags straight from global, L2-hot)
// LDS: Qs[0,8192) Ss[8192,24576)  = 48 KB
// ---------------------------------------------------------------------------
__global__ __launch_bounds__(256, 2)
void combine_kernel(const u16* __restrict__ Qg, const u16* __restrict__ Sb16,
                    const u16* __restrict__ O1g, const u16* __restrict__ Woh,
                    const float* __restrict__ bo, float* __restrict__ y)
{
  __shared__ __align__(16) u16 L[24576];
  const int c = blockIdx.x, b = blockIdx.y, z = blockIdx.z;
  const int cg = b * kNC + c;
  const int R0 = cg * kC;
  const int tid = threadIdx.x, w = tid >> 6, lane = tid & 63;
  const int fr = lane & 15, qd = lane >> 4;

  {
    const int rr = lane >> 2, c8 = (lane & 3) * 8;
    const u16* gq = Qg + (size_t)(R0 + rr) * kM + w * 32 + c8;
    u16* lq = &L[w * 2048];
#pragma unroll
    for (int s = 0; s < 4; ++s)
      gl_lds16(gq + (size_t)s * 16 * kM, lq + s * 512);
    const u16* gs = Sb16 + (size_t)cg * 16384 + (size_t)rr * kM + w * 32 + c8;
    u16* ls = &L[8192 + w * 4096];
#pragma unroll
    for (int s = 0; s < 8; ++s)
      gl_lds16(gs + (size_t)s * 16 * kM, ls + s * 512);
  }
  const int mB = (w >> 1) * 32, nB = (w & 1) * 64;
  u16 o1h[2][4][4];
#pragma unroll
  for (int mi = 0; mi < 2; ++mi)
#pragma unroll
    for (int ni = 0; ni < 4; ++ni)
#pragma unroll
      for (int r = 0; r < 4; ++r)
        o1h[mi][ni][r] = O1g[(size_t)(R0 + mB + mi * 16 + qd * 4 + r) * kM + nB + ni * 16 + fr];
  __syncthreads();

  // O2 = Q S^T
  f32x4 o2[2][4] = {};
#pragma unroll
  for (int kp = 0; kp < 4; ++kp) {
    bf16x8 aq[2], bs[4];
#pragma unroll
    for (int mi = 0; mi < 2; ++mi) aq[mi] = *(const bf16x8*)&L[kp * 2048 + (mB + mi * 16 + fr) * 32 + qd * 8];
#pragma unroll
    for (int ni = 0; ni < 4; ++ni) bs[ni] = *(const bf16x8*)&L[8192 + kp * 4096 + (nB + ni * 16 + fr) * 32 + qd * 8];
#pragma unroll
    for (int mi = 0; mi < 2; ++mi)
#pragma unroll
      for (int ni = 0; ni < 4; ++ni)
        o2[mi][ni] = mf(aq[mi], bs[ni], o2[mi][ni]);
  }
  __syncthreads();

  // Out panels [t][32f] into L[0..8192)
#pragma unroll
  for (int mi = 0; mi < 2; ++mi)
#pragma unroll
    for (int r = 0; r < 4; ++r) {
      const int t = mB + mi * 16 + qd * 4 + r;
      const float dt = exp2f((float)t * kLog2d);
#pragma unroll
      for (int ni = 0; ni < 4; ++ni) {
        const int f = nB + ni * 16 + fr;
        const float ov = fmaf(dt, o2[mi][ni][r], bf2f(o1h[mi][ni][r]));
        L[(f >> 5) * 2048 + t * 32 + (f & 31)] = f2bf(ov);
      }
    }
  __syncthreads();

  // y[t][d] = Out @ Woh^T + bo ; wave d-range 128 within z-half, 2 halves of 64
#pragma unroll 1
  for (int h = 0; h < 2; ++h) {
    const int d0 = z * 512 + w * 128 + h * 64;
    f32x4 fy[4][4] = {};
#pragma unroll
    for (int kp = 0; kp < 4; ++kp) {
      bf16x8 ao[4], bw[4];
#pragma unroll
      for (int mi = 0; mi < 4; ++mi) ao[mi] = *(const bf16x8*)&L[kp * 2048 + (mi * 16 + fr) * 32 + qd * 8];
#pragma unroll
      for (int nj = 0; nj < 4; ++nj)
        bw[nj] = *(const bf16x8*)&Woh[(size_t)(d0 + nj * 16 + fr) * kM + kp * 32 + qd * 8];
#pragma unroll
      for (int mi = 0; mi < 4; ++mi)
#pragma unroll
        for (int nj = 0; nj < 4; ++nj)
          fy[mi][nj] = mf(ao[mi], bw[nj], fy[mi][nj]);
    }
#pragma unroll
    for (int nj = 0; nj < 4; ++nj) {
      const int d = d0 + nj * 16 + fr;
      const float bb = bo[d];
#pragma unroll
      for (int mi = 0; mi < 4; ++mi)
#pragma unroll
        for (int r = 0; r < 4; ++r)
          y[(size_t)(R0 + mi * 16 + qd * 4 + r) * kD + d] = fy[mi][nj][r] + bb;
    }
  }
}

// ---------------------------------------------------------------------------
extern "C" void kernel_launch(void* const* d_in, const int* in_sizes, int n_in,
                              void* d_out, int out_size, void* d_ws, size_t ws_size,
                              hipStream_t stream) {
  const float* x  = (const float*)d_in[0];
  const float* Wk = (const float*)d_in[1];
  const float* bk = (const float*)d_in[2];
  const float* Wv = (const float*)d_in[3];
  const float* bv = (const float*)d_in[4];
  const float* Wq = (const float*)d_in[5];
  const float* bq = (const float*)d_in[6];
  const float* Wo = (const float*)d_in[7];
  const float* bo = (const float*)d_in[8];

  char* wsp = (char*)d_ws;
  u16* Wkvq = (u16*)wsp;   wsp += (size_t)384 * 1024 * 2;
  u16* Woh  = (u16*)wsp;   wsp += (size_t)1024 * 128 * 2;
  u16* Qg   = (u16*)wsp;   wsp += (size_t)kRS * kM * 2;
  u16* Kg   = (u16*)wsp;   wsp += (size_t)kRS * kM * 2;
  u16* VtG  = (u16*)wsp;   wsp += (size_t)kNCg * 8192 * 2;
  u16* KwtG = (u16*)wsp;   wsp += (size_t)kNCg * 8192 * 2;
  u16* O1g  = (u16*)wsp;   wsp += (size_t)kRS * kM * 2;
  float* SU = (float*)wsp; wsp += (size_t)kNCg * 16384 * 4;
  u16* Sb16 = (u16*)wsp;   wsp += (size_t)kNCg * 16384 * 2;

  float* y = (float*)d_out;
  float* state_out = y + (size_t)kRS * kD;

  dim3 blk(256);
  cast_w_kernel<<<dim3(512), blk, 0, stream>>>(Wk, Wv, Wq, Wo, Wkvq, Woh);
  proj_kernel<<<dim3(kRS / 128, 4), blk, 0, stream>>>(x, Wkvq, bk, bv, bq, Qg, Kg, VtG, KwtG);
  intra_kernel<<<dim3(kNC, kB, 2), blk, 0, stream>>>(Qg, Kg, VtG, KwtG, O1g, SU);
  scan_kernel<<<dim3(kB * 16384 / 256), blk, 0, stream>>>(SU, Sb16, state_out);
  combine_kernel<<<dim3(kNC, kB, 2), blk, 0, stream>>>(Qg, Sb16, O1g, Woh, bo, y);
}